// Round 1
// baseline (1007.093 us; speedup 1.0000x reference)
//
#include <hip/hip_runtime.h>
#include <hip/hip_bf16.h>
#include <math.h>

// Problem sizes (fixed by the reference)
#define BS 256
#define SEQ 512
#define HID 1024
#define EMB 300
#define VOC 32000
#define XCAT 2368          // 300 + 1024 + 1024 = 2348, padded to 74*32
#define XREAL 2348

typedef unsigned short u16;
typedef short bf16x8 __attribute__((ext_vector_type(8)));
typedef float f32x4 __attribute__((ext_vector_type(4)));

__device__ __forceinline__ u16 f2bf(float f) {
    union { float f; unsigned int u; } v; v.f = f;
    unsigned int u = v.u;
    unsigned int r = (u + 0x7FFFu + ((u >> 16) & 1u)) >> 16;  // RNE
    return (u16)r;
}

// ---------------------------------------------------------------------------
// Kernel 1: fused attention (online softmax, single pass over enc) + x_cat
// one block per batch row; 1024 threads = 16 waves; wave w handles s = w+16t
// ---------------------------------------------------------------------------
__global__ __launch_bounds__(1024) void attn_kernel(
    const int* __restrict__ idx,
    const float* __restrict__ hiddens,    // (BS,HID)
    const float* __restrict__ enc,        // (BS,SEQ,HID)
    const float* __restrict__ emb_table,  // (VOC,EMB)
    float* __restrict__ attn_out,         // (BS,SEQ)
    u16* __restrict__ xcat)               // (BS,XCAT) bf16
{
    __shared__ float ctx_sh[8][HID];      // 32 KB
    __shared__ float ctx_red[HID];
    __shared__ float energy_sh[SEQ];
    __shared__ float mw_sh[16], lw_sh[16];

    const int b = blockIdx.x;
    const int tid = threadIdx.x;
    const int wave = tid >> 6, lane = tid & 63;
    const float* encb = enc + (size_t)b * SEQ * HID;
    const float* hb = hiddens + (size_t)b * HID;

    // lane owns h indices 4*lane + 256*c, c=0..3
    float4 hreg[4];
#pragma unroll
    for (int c = 0; c < 4; ++c)
        hreg[c] = *(const float4*)(hb + 4 * lane + 256 * c);

    float m = -INFINITY, l = 0.f;
    float4 ctx[4];
#pragma unroll
    for (int c = 0; c < 4; ++c) ctx[c] = make_float4(0.f, 0.f, 0.f, 0.f);

    // prefetch s = wave
    float4 ev[4], nv[4];
    {
        const float* p0 = encb + (size_t)wave * HID + 4 * lane;
#pragma unroll
        for (int c = 0; c < 4; ++c) ev[c] = *(const float4*)(p0 + 256 * c);
    }

    for (int t = 0; t < 32; ++t) {
        const int s = wave + 16 * t;
        if (t < 31) {
            const float* pn = encb + (size_t)(s + 16) * HID + 4 * lane;
#pragma unroll
            for (int c = 0; c < 4; ++c) nv[c] = *(const float4*)(pn + 256 * c);
        }
        float part = 0.f;
#pragma unroll
        for (int c = 0; c < 4; ++c) {
            part += ev[c].x * hreg[c].x + ev[c].y * hreg[c].y
                  + ev[c].z * hreg[c].z + ev[c].w * hreg[c].w;
        }
#pragma unroll
        for (int off = 32; off > 0; off >>= 1)
            part += __shfl_xor(part, off);
        const float e = part;
        if (lane == 0) energy_sh[s] = e;

        const float mnew = fmaxf(m, e);
        const float scale = __expf(m - mnew);   // 0 on first iter (m=-inf)
        const float pp = __expf(e - mnew);
        l = l * scale + pp;
#pragma unroll
        for (int c = 0; c < 4; ++c) {
            ctx[c].x = ctx[c].x * scale + pp * ev[c].x;
            ctx[c].y = ctx[c].y * scale + pp * ev[c].y;
            ctx[c].z = ctx[c].z * scale + pp * ev[c].z;
            ctx[c].w = ctx[c].w * scale + pp * ev[c].w;
        }
        m = mnew;
#pragma unroll
        for (int c = 0; c < 4; ++c) ev[c] = nv[c];
    }

    if (lane == 0) { mw_sh[wave] = m; lw_sh[wave] = l; }
    __syncthreads();

    float mtot = -INFINITY;
#pragma unroll
    for (int w = 0; w < 16; ++w) mtot = fmaxf(mtot, mw_sh[w]);
    float ltot = 0.f;
#pragma unroll
    for (int w = 0; w < 16; ++w) ltot += lw_sh[w] * __expf(mw_sh[w] - mtot);
    const float cw = __expf(m - mtot);   // this wave's rescale coefficient

    // two-stage ctx merge into ctx_sh[0..7]
    if (wave >= 8) {
#pragma unroll
        for (int c = 0; c < 4; ++c) {
            float4 v = make_float4(ctx[c].x * cw, ctx[c].y * cw,
                                   ctx[c].z * cw, ctx[c].w * cw);
            *(float4*)&ctx_sh[wave - 8][4 * lane + 256 * c] = v;
        }
    }
    __syncthreads();
    if (wave < 8) {
#pragma unroll
        for (int c = 0; c < 4; ++c) {
            float4* dst = (float4*)&ctx_sh[wave][4 * lane + 256 * c];
            float4 cur = *dst;
            cur.x += ctx[c].x * cw; cur.y += ctx[c].y * cw;
            cur.z += ctx[c].z * cw; cur.w += ctx[c].w * cw;
            *dst = cur;
        }
    }
    __syncthreads();

    // reduce 8 partial ctx rows -> ctx_red
    {
        float ssum = 0.f;
#pragma unroll
        for (int w = 0; w < 8; ++w) ssum += ctx_sh[w][tid];
        ctx_red[tid] = ssum / ltot;
    }

    // attn output (exact softmax from stored energies)
    const float inv_l = 1.f / ltot;
    if (tid < SEQ)
        attn_out[(size_t)b * SEQ + tid] = __expf(energy_sh[tid] - mtot) * inv_l;
    __syncthreads();

    // x_cat = [emb(300) | ctx(1024) | h(1024) | 0-pad(20)] as bf16
    const int iidx = idx[b];
    const size_t row_off = (size_t)b * XCAT;
    for (int i = tid; i < XCAT; i += 1024) {
        float v;
        if (i < EMB)            v = emb_table[(size_t)iidx * EMB + i];
        else if (i < EMB + HID) v = ctx_red[i - EMB];
        else if (i < XREAL)     v = hb[i - (EMB + HID)];
        else                    v = 0.f;
        xcat[row_off + i] = f2bf(v);
    }
}

// ---------------------------------------------------------------------------
// Kernel 2: h_new = tanh(x_cat @ [W_ih|W_hh]^T + b_ih + b_hh)
// M=256 (full), N=1024, K=2368 (padded). Block tile 256x64, 4 waves.
// ---------------------------------------------------------------------------
__global__ __launch_bounds__(256) void rnn_gemm(
    const u16* __restrict__ A,      // (256,XCAT) bf16
    const float* __restrict__ W_ih, // (1024,1324)
    const float* __restrict__ W_hh, // (1024,1024)
    const float* __restrict__ b_ih,
    const float* __restrict__ b_hh,
    float* __restrict__ outh,       // (256,1024) fp32 -> d_out
    u16* __restrict__ hbf)          // (256,1024) bf16 -> ws
{
    constexpr int LDSS = 72;
    __shared__ u16 Ash[256 * LDSS];
    __shared__ u16 Bsh[64 * LDSS];
    const int tid = threadIdx.x;
    const int wave = tid >> 6, lane = tid & 63;
    const int lane15 = lane & 15, quad = lane >> 4;
    const int nblk = blockIdx.x;
    const int arow = tid >> 3;          // 0..31
    const int k0 = (tid & 7) * 8;

    f32x4 acc[4][4];
#pragma unroll
    for (int i = 0; i < 4; ++i)
#pragma unroll
        for (int j = 0; j < 4; ++j) acc[i][j] = f32x4{0.f, 0.f, 0.f, 0.f};

    for (int kt = 0; kt < XCAT / 64; ++kt) {
#pragma unroll
        for (int p = 0; p < 8; ++p) {
            const int row = p * 32 + arow;
            uint4 v = *(const uint4*)(A + (size_t)row * XCAT + kt * 64 + k0);
            *(uint4*)&Ash[row * LDSS + k0] = v;
        }
#pragma unroll
        for (int p = 0; p < 2; ++p) {
            const int row = p * 32 + arow;
            const int j = nblk * 64 + row;
            const int kbase = kt * 64 + k0;
            alignas(16) u16 tmp[8];
#pragma unroll
            for (int e = 0; e < 8; ++e) {
                const int kg = kbase + e;
                float v;
                if (kg < EMB + HID)   v = W_ih[(size_t)j * (EMB + HID) + kg];
                else if (kg < XREAL)  v = W_hh[(size_t)j * HID + (kg - (EMB + HID))];
                else                  v = 0.f;
                tmp[e] = f2bf(v);
            }
            *(uint4*)&Bsh[row * LDSS + k0] = *(const uint4*)tmp;
        }
        __syncthreads();
#pragma unroll
        for (int ks = 0; ks < 64; ks += 32) {
            bf16x8 af[4], bfr[4];
#pragma unroll
            for (int mi = 0; mi < 4; ++mi)
                af[mi] = *(const bf16x8*)&Ash[(wave * 64 + mi * 16 + lane15) * LDSS + ks + quad * 8];
#pragma unroll
            for (int ni = 0; ni < 4; ++ni)
                bfr[ni] = *(const bf16x8*)&Bsh[(ni * 16 + lane15) * LDSS + ks + quad * 8];
#pragma unroll
            for (int mi = 0; mi < 4; ++mi)
#pragma unroll
                for (int ni = 0; ni < 4; ++ni)
                    acc[mi][ni] = __builtin_amdgcn_mfma_f32_16x16x32_bf16(
                        af[mi], bfr[ni], acc[mi][ni], 0, 0, 0);
        }
        __syncthreads();
    }

#pragma unroll
    for (int ni = 0; ni < 4; ++ni) {
        const int n = nblk * 64 + ni * 16 + lane15;
        const float bv = b_ih[n] + b_hh[n];
#pragma unroll
        for (int mi = 0; mi < 4; ++mi)
#pragma unroll
            for (int r = 0; r < 4; ++r) {
                const int mm = wave * 64 + mi * 16 + quad * 4 + r;
                const float hv = tanhf(acc[mi][ni][r] + bv);
                outh[(size_t)mm * HID + n] = hv;
                hbf[(size_t)mm * HID + n] = f2bf(hv);
            }
    }
}

// ---------------------------------------------------------------------------
// Kernel 3: logits = h_new @ fc_W^T + fc_b
// M=256 (full), N=32000, K=1024. Block tile 256x64, 4 waves. fc_W fp32->bf16
// converted in-register during LDS staging (fc_W read exactly once from HBM).
// ---------------------------------------------------------------------------
__global__ __launch_bounds__(256) void fc_gemm(
    const u16* __restrict__ A,      // (256,1024) bf16
    const float* __restrict__ W,    // (32000,1024)
    const float* __restrict__ bias, // (32000)
    float* __restrict__ out)        // (256,32000)
{
    constexpr int K = 1024, LDSS = 72;
    __shared__ u16 Ash[256 * LDSS];
    __shared__ u16 Bsh[64 * LDSS];
    const int tid = threadIdx.x;
    const int wave = tid >> 6, lane = tid & 63;
    const int lane15 = lane & 15, quad = lane >> 4;
    const int nblk = blockIdx.x;
    const int arow = tid >> 3;
    const int k0 = (tid & 7) * 8;

    f32x4 acc[4][4];
#pragma unroll
    for (int i = 0; i < 4; ++i)
#pragma unroll
        for (int j = 0; j < 4; ++j) acc[i][j] = f32x4{0.f, 0.f, 0.f, 0.f};

    for (int kt = 0; kt < K / 64; ++kt) {
#pragma unroll
        for (int p = 0; p < 8; ++p) {
            const int row = p * 32 + arow;
            uint4 v = *(const uint4*)(A + (size_t)row * K + kt * 64 + k0);
            *(uint4*)&Ash[row * LDSS + k0] = v;
        }
#pragma unroll
        for (int p = 0; p < 2; ++p) {
            const int row = p * 32 + arow;
            const float* src = W + (size_t)(nblk * 64 + row) * K + kt * 64 + k0;
            alignas(16) u16 tmp[8];
            float4 f0 = *(const float4*)(src);
            float4 f1 = *(const float4*)(src + 4);
            tmp[0] = f2bf(f0.x); tmp[1] = f2bf(f0.y);
            tmp[2] = f2bf(f0.z); tmp[3] = f2bf(f0.w);
            tmp[4] = f2bf(f1.x); tmp[5] = f2bf(f1.y);
            tmp[6] = f2bf(f1.z); tmp[7] = f2bf(f1.w);
            *(uint4*)&Bsh[row * LDSS + k0] = *(const uint4*)tmp;
        }
        __syncthreads();
#pragma unroll
        for (int ks = 0; ks < 64; ks += 32) {
            bf16x8 af[4], bfr[4];
#pragma unroll
            for (int mi = 0; mi < 4; ++mi)
                af[mi] = *(const bf16x8*)&Ash[(wave * 64 + mi * 16 + lane15) * LDSS + ks + quad * 8];
#pragma unroll
            for (int ni = 0; ni < 4; ++ni)
                bfr[ni] = *(const bf16x8*)&Bsh[(ni * 16 + lane15) * LDSS + ks + quad * 8];
#pragma unroll
            for (int mi = 0; mi < 4; ++mi)
#pragma unroll
                for (int ni = 0; ni < 4; ++ni)
                    acc[mi][ni] = __builtin_amdgcn_mfma_f32_16x16x32_bf16(
                        af[mi], bfr[ni], acc[mi][ni], 0, 0, 0);
        }
        __syncthreads();
    }

#pragma unroll
    for (int ni = 0; ni < 4; ++ni) {
        const int n = nblk * 64 + ni * 16 + lane15;
        const float bv = bias[n];
#pragma unroll
        for (int mi = 0; mi < 4; ++mi)
#pragma unroll
            for (int r = 0; r < 4; ++r) {
                const int mm = wave * 64 + mi * 16 + quad * 4 + r;
                out[(size_t)mm * VOC + n] = acc[mi][ni][r] + bv;
            }
    }
}

// ---------------------------------------------------------------------------
extern "C" void kernel_launch(void* const* d_in, const int* in_sizes, int n_in,
                              void* d_out, int out_size, void* d_ws, size_t ws_size,
                              hipStream_t stream) {
    (void)in_sizes; (void)n_in; (void)out_size; (void)ws_size;
    const int*   idx  = (const int*)d_in[0];
    const float* hid  = (const float*)d_in[1];
    const float* enc  = (const float*)d_in[2];
    const float* emb  = (const float*)d_in[3];
    const float* W_ih = (const float*)d_in[4];
    const float* b_ih = (const float*)d_in[5];
    const float* W_hh = (const float*)d_in[6];
    const float* b_hh = (const float*)d_in[7];
    const float* fc_W = (const float*)d_in[8];
    const float* fc_b = (const float*)d_in[9];

    float* out    = (float*)d_out;
    float* logits = out;                                   // 256*32000
    float* hnew   = out + (size_t)BS * VOC;                // 256*1024
    float* attn   = out + (size_t)BS * VOC + BS * HID;     // 256*512

    u16* xcat = (u16*)d_ws;                                // 256*2368 bf16
    u16* hbf  = (u16*)d_ws + (size_t)BS * XCAT;            // 256*1024 bf16

    hipLaunchKernelGGL(attn_kernel, dim3(BS), dim3(1024), 0, stream,
                       idx, hid, enc, emb, attn, xcat);
    hipLaunchKernelGGL(rnn_gemm, dim3(HID / 64), dim3(256), 0, stream,
                       xcat, W_ih, W_hh, b_ih, b_hh, hnew, hbf);
    hipLaunchKernelGGL(fc_gemm, dim3(VOC / 64), dim3(256), 0, stream,
                       hbf, fc_W, fc_b, logits);
}

// Round 2
// 851.828 us; speedup vs baseline: 1.1823x; 1.1823x over previous
//
#include <hip/hip_runtime.h>
#include <hip/hip_bf16.h>
#include <math.h>

// Problem sizes (fixed by the reference)
#define BS 256
#define SEQ 512
#define HID 1024
#define EMB 300
#define VOC 32000
#define XCAT 2368          // 300 + 1024 + 1024 = 2348, padded to 74*32
#define XREAL 2348
#define IH_K (EMB + HID)   // 1324

typedef unsigned short u16;
typedef short bf16x8 __attribute__((ext_vector_type(8)));
typedef float f32x4 __attribute__((ext_vector_type(4)));

__device__ __forceinline__ u16 f2bf(float f) {
    union { float f; unsigned int u; } v; v.f = f;
    unsigned int u = v.u;
    unsigned int r = (u + 0x7FFFu + ((u >> 16) & 1u)) >> 16;  // RNE
    return (u16)r;
}

// ---------------------------------------------------------------------------
// Kernel 0: pack [W_ih | W_hh | 0pad] into bf16 Wp (HID x XCAT)
// ---------------------------------------------------------------------------
__global__ __launch_bounds__(256) void pack_w(
    const float* __restrict__ W_ih,   // (HID, IH_K)
    const float* __restrict__ W_hh,   // (HID, HID)
    u16* __restrict__ Wp)             // (HID, XCAT)
{
    const int t = blockIdx.x * 256 + threadIdx.x;
    const int base = t * 8;                       // grid sized exactly
    const int n = base / XCAT;
    const int k0 = base - n * XCAT;
    alignas(16) u16 tmp[8];
#pragma unroll
    for (int e = 0; e < 8; ++e) {
        const int kg = k0 + e;
        float v;
        if (kg < IH_K)       v = W_ih[(size_t)n * IH_K + kg];
        else if (kg < XREAL) v = W_hh[(size_t)n * HID + (kg - IH_K)];
        else                 v = 0.f;
        tmp[e] = f2bf(v);
    }
    *(uint4*)(Wp + base) = *(const uint4*)tmp;
}

// ---------------------------------------------------------------------------
// Kernel 1: fused attention (online softmax, single pass over enc) + x_cat
// one block per batch row; 1024 threads = 16 waves; wave w handles s = w+16t
// ---------------------------------------------------------------------------
__global__ __launch_bounds__(1024) void attn_kernel(
    const int* __restrict__ idx,
    const float* __restrict__ hiddens,    // (BS,HID)
    const float* __restrict__ enc,        // (BS,SEQ,HID)
    const float* __restrict__ emb_table,  // (VOC,EMB)
    float* __restrict__ attn_out,         // (BS,SEQ)
    u16* __restrict__ xcat)               // (BS,XCAT) bf16
{
    __shared__ float ctx_sh[8][HID];      // 32 KB
    __shared__ float ctx_red[HID];
    __shared__ float energy_sh[SEQ];
    __shared__ float mw_sh[16], lw_sh[16];

    const int b = blockIdx.x;
    const int tid = threadIdx.x;
    const int wave = tid >> 6, lane = tid & 63;
    const float* encb = enc + (size_t)b * SEQ * HID;
    const float* hb = hiddens + (size_t)b * HID;

    float4 hreg[4];
#pragma unroll
    for (int c = 0; c < 4; ++c)
        hreg[c] = *(const float4*)(hb + 4 * lane + 256 * c);

    float m = -INFINITY, l = 0.f;
    float4 ctx[4];
#pragma unroll
    for (int c = 0; c < 4; ++c) ctx[c] = make_float4(0.f, 0.f, 0.f, 0.f);

    float4 ev[4], nv[4];
    {
        const float* p0 = encb + (size_t)wave * HID + 4 * lane;
#pragma unroll
        for (int c = 0; c < 4; ++c) ev[c] = *(const float4*)(p0 + 256 * c);
    }

    for (int t = 0; t < 32; ++t) {
        const int s = wave + 16 * t;
        if (t < 31) {
            const float* pn = encb + (size_t)(s + 16) * HID + 4 * lane;
#pragma unroll
            for (int c = 0; c < 4; ++c) nv[c] = *(const float4*)(pn + 256 * c);
        }
        float part = 0.f;
#pragma unroll
        for (int c = 0; c < 4; ++c) {
            part += ev[c].x * hreg[c].x + ev[c].y * hreg[c].y
                  + ev[c].z * hreg[c].z + ev[c].w * hreg[c].w;
        }
#pragma unroll
        for (int off = 32; off > 0; off >>= 1)
            part += __shfl_xor(part, off);
        const float e = part;
        if (lane == 0) energy_sh[s] = e;

        const float mnew = fmaxf(m, e);
        const float scale = __expf(m - mnew);
        const float pp = __expf(e - mnew);
        l = l * scale + pp;
#pragma unroll
        for (int c = 0; c < 4; ++c) {
            ctx[c].x = ctx[c].x * scale + pp * ev[c].x;
            ctx[c].y = ctx[c].y * scale + pp * ev[c].y;
            ctx[c].z = ctx[c].z * scale + pp * ev[c].z;
            ctx[c].w = ctx[c].w * scale + pp * ev[c].w;
        }
        m = mnew;
#pragma unroll
        for (int c = 0; c < 4; ++c) ev[c] = nv[c];
    }

    if (lane == 0) { mw_sh[wave] = m; lw_sh[wave] = l; }
    __syncthreads();

    float mtot = -INFINITY;
#pragma unroll
    for (int w = 0; w < 16; ++w) mtot = fmaxf(mtot, mw_sh[w]);
    float ltot = 0.f;
#pragma unroll
    for (int w = 0; w < 16; ++w) ltot += lw_sh[w] * __expf(mw_sh[w] - mtot);
    const float cw = __expf(m - mtot);

    if (wave >= 8) {
#pragma unroll
        for (int c = 0; c < 4; ++c) {
            float4 v = make_float4(ctx[c].x * cw, ctx[c].y * cw,
                                   ctx[c].z * cw, ctx[c].w * cw);
            *(float4*)&ctx_sh[wave - 8][4 * lane + 256 * c] = v;
        }
    }
    __syncthreads();
    if (wave < 8) {
#pragma unroll
        for (int c = 0; c < 4; ++c) {
            float4* dst = (float4*)&ctx_sh[wave][4 * lane + 256 * c];
            float4 cur = *dst;
            cur.x += ctx[c].x * cw; cur.y += ctx[c].y * cw;
            cur.z += ctx[c].z * cw; cur.w += ctx[c].w * cw;
            *dst = cur;
        }
    }
    __syncthreads();

    {
        float ssum = 0.f;
#pragma unroll
        for (int w = 0; w < 8; ++w) ssum += ctx_sh[w][tid];
        ctx_red[tid] = ssum / ltot;
    }

    const float inv_l = 1.f / ltot;
    if (tid < SEQ)
        attn_out[(size_t)b * SEQ + tid] = __expf(energy_sh[tid] - mtot) * inv_l;
    __syncthreads();

    const int iidx = idx[b];
    const size_t row_off = (size_t)b * XCAT;
    for (int i = tid; i < XCAT; i += 1024) {
        float v;
        if (i < EMB)            v = emb_table[(size_t)iidx * EMB + i];
        else if (i < EMB + HID) v = ctx_red[i - EMB];
        else if (i < XREAL)     v = hb[i - (EMB + HID)];
        else                    v = 0.f;
        xcat[row_off + i] = f2bf(v);
    }
}

// ---------------------------------------------------------------------------
// Kernel 2: h_new = tanh(xcat @ Wp^T + b_ih + b_hh)
// LDS-free: 1024 waves, each owns a 16x16 output tile; operands are
// L2-resident (xcat 1.2 MB, Wp 4.8 MB). 256 blocks x 256 threads.
// ---------------------------------------------------------------------------
__global__ __launch_bounds__(256) void rnn_gemm2(
    const u16* __restrict__ A,      // xcat (BS, XCAT) bf16
    const u16* __restrict__ Wp,     // (HID, XCAT) bf16
    const float* __restrict__ b_ih,
    const float* __restrict__ b_hh,
    float* __restrict__ outh,       // (BS, HID) fp32 -> d_out
    u16* __restrict__ hbf)          // (BS, HID) bf16 -> ws
{
    const int tid = threadIdx.x;
    const int wave = tid >> 6, lane = tid & 63;
    const int lane15 = lane & 15, quad = lane >> 4;
    const int gw = blockIdx.x * 4 + wave;     // 0..1023
    const int mt = gw >> 6;                   // 0..15
    const int nt = gw & 63;                   // 0..63
    const int m0 = mt * 16, n0 = nt * 16;

    const u16* Ap = A  + (size_t)(m0 + lane15) * XCAT + quad * 8;
    const u16* Bp = Wp + (size_t)(n0 + lane15) * XCAT + quad * 8;

    f32x4 acc = f32x4{0.f, 0.f, 0.f, 0.f};
#pragma unroll 2
    for (int k = 0; k < XCAT; k += 32) {
        bf16x8 a  = *(const bf16x8*)(Ap + k);
        bf16x8 bv = *(const bf16x8*)(Bp + k);
        acc = __builtin_amdgcn_mfma_f32_16x16x32_bf16(a, bv, acc, 0, 0, 0);
    }

    const int n = n0 + lane15;
    const float bv = b_ih[n] + b_hh[n];
#pragma unroll
    for (int r = 0; r < 4; ++r) {
        const int mm = m0 + quad * 4 + r;
        const float hv = tanhf(acc[r] + bv);
        outh[(size_t)mm * HID + n] = hv;
        hbf[(size_t)mm * HID + n] = f2bf(hv);
    }
}

// ---------------------------------------------------------------------------
// Kernel 3: logits = h_new @ fc_W^T + fc_b
// M=256 (full), N=32000, K=1024. Block = 256M x 64N, 4 waves x (64M x 64N).
// A (bf16, 512 KB, L2-resident) loaded straight to fragments — no Ash, no
// A-barrier. LDS only for the fp32->bf16-converted B tile (9 KB).
// ---------------------------------------------------------------------------
__global__ __launch_bounds__(256) void fc_gemm2(
    const u16* __restrict__ A,      // (256,1024) bf16
    const float* __restrict__ W,    // (32000,1024)
    const float* __restrict__ bias, // (32000)
    float* __restrict__ out)        // (256,32000)
{
    constexpr int K = 1024, LDSS = 72;
    __shared__ u16 Bsh[64 * LDSS];
    const int tid = threadIdx.x;
    const int wave = tid >> 6, lane = tid & 63;
    const int lane15 = lane & 15, quad = lane >> 4;
    const int nblk = blockIdx.x;
    const int arow = tid >> 3;          // 0..31
    const int k0 = (tid & 7) * 8;

    f32x4 acc[4][4];
#pragma unroll
    for (int i = 0; i < 4; ++i)
#pragma unroll
        for (int j = 0; j < 4; ++j) acc[i][j] = f32x4{0.f, 0.f, 0.f, 0.f};

    const u16* Abase = A + (size_t)(wave * 64 + lane15) * K + quad * 8;

    for (int kt = 0; kt < K / 64; ++kt) {
        // stage + convert B tile: 64 rows x 64 cols
#pragma unroll
        for (int p = 0; p < 2; ++p) {
            const int row = p * 32 + arow;
            const float* src = W + (size_t)(nblk * 64 + row) * K + kt * 64 + k0;
            alignas(16) u16 tmp[8];
            float4 f0 = *(const float4*)(src);
            float4 f1 = *(const float4*)(src + 4);
            tmp[0] = f2bf(f0.x); tmp[1] = f2bf(f0.y);
            tmp[2] = f2bf(f0.z); tmp[3] = f2bf(f0.w);
            tmp[4] = f2bf(f1.x); tmp[5] = f2bf(f1.y);
            tmp[6] = f2bf(f1.z); tmp[7] = f2bf(f1.w);
            *(uint4*)&Bsh[row * LDSS + k0] = *(const uint4*)tmp;
        }
        __syncthreads();
#pragma unroll
        for (int ks = 0; ks < 64; ks += 32) {
            bf16x8 af[4], bfr[4];
#pragma unroll
            for (int mi = 0; mi < 4; ++mi)
                af[mi] = *(const bf16x8*)(Abase + (size_t)mi * 16 * K + kt * 64 + ks);
#pragma unroll
            for (int ni = 0; ni < 4; ++ni)
                bfr[ni] = *(const bf16x8*)&Bsh[(ni * 16 + lane15) * LDSS + ks + quad * 8];
#pragma unroll
            for (int mi = 0; mi < 4; ++mi)
#pragma unroll
                for (int ni = 0; ni < 4; ++ni)
                    acc[mi][ni] = __builtin_amdgcn_mfma_f32_16x16x32_bf16(
                        af[mi], bfr[ni], acc[mi][ni], 0, 0, 0);
        }
        __syncthreads();
    }

#pragma unroll
    for (int ni = 0; ni < 4; ++ni) {
        const int n = nblk * 64 + ni * 16 + lane15;
        const float bv = bias[n];
#pragma unroll
        for (int mi = 0; mi < 4; ++mi)
#pragma unroll
            for (int r = 0; r < 4; ++r) {
                const int mm = wave * 64 + mi * 16 + quad * 4 + r;
                __builtin_nontemporal_store(acc[mi][ni][r] + bv,
                                            &out[(size_t)mm * VOC + n]);
            }
    }
}

// ---------------------------------------------------------------------------
extern "C" void kernel_launch(void* const* d_in, const int* in_sizes, int n_in,
                              void* d_out, int out_size, void* d_ws, size_t ws_size,
                              hipStream_t stream) {
    (void)in_sizes; (void)n_in; (void)out_size; (void)ws_size;
    const int*   idx  = (const int*)d_in[0];
    const float* hid  = (const float*)d_in[1];
    const float* enc  = (const float*)d_in[2];
    const float* emb  = (const float*)d_in[3];
    const float* W_ih = (const float*)d_in[4];
    const float* b_ih = (const float*)d_in[5];
    const float* W_hh = (const float*)d_in[6];
    const float* b_hh = (const float*)d_in[7];
    const float* fc_W = (const float*)d_in[8];
    const float* fc_b = (const float*)d_in[9];

    float* out    = (float*)d_out;
    float* logits = out;                                   // 256*32000
    float* hnew   = out + (size_t)BS * VOC;                // 256*1024
    float* attn   = out + (size_t)BS * VOC + BS * HID;     // 256*512

    u16* xcat = (u16*)d_ws;                                // 256*2368
    u16* hbf  = xcat + (size_t)BS * XCAT;                  // 256*1024
    u16* Wp   = hbf + (size_t)BS * HID;                    // 1024*2368

    hipLaunchKernelGGL(pack_w, dim3((HID * XCAT) / (256 * 8)), dim3(256), 0, stream,
                       W_ih, W_hh, Wp);
    hipLaunchKernelGGL(attn_kernel, dim3(BS), dim3(1024), 0, stream,
                       idx, hid, enc, emb, attn, xcat);
    hipLaunchKernelGGL(rnn_gemm2, dim3(BS), dim3(256), 0, stream,
                       xcat, Wp, b_ih, b_hh, hnew, hbf);
    hipLaunchKernelGGL(fc_gemm2, dim3(VOC / 64), dim3(256), 0, stream,
                       hbf, fc_W, fc_b, logits);
}